// Round 5
// baseline (549.195 us; speedup 1.0000x reference)
//
#include <hip/hip_runtime.h>

using u16 = unsigned short;
using f16 = _Float16;
typedef __attribute__((ext_vector_type(8))) _Float16 f16x8;
typedef __attribute__((ext_vector_type(4))) _Float16 f16x4;
typedef __attribute__((ext_vector_type(4))) float f32x4;

#define DEV static __device__ __forceinline__

// async global->LDS, 16B per lane. LDS dest must be wave-uniform base + lane*16.
DEV void gload16(const void* g, const void* l) {
    __builtin_amdgcn_global_load_lds((const __attribute__((address_space(1))) void*)g,
                                     (__attribute__((address_space(3))) void*)l,
                                     16, 0, 0);
}

DEV f32x4 mfma16(f16x8 a, f16x8 b, f32x4 c) {
    return __builtin_amdgcn_mfma_f32_16x16x32_f16(a, b, c, 0, 0, 0);
}

// XOR-swizzle involution: staging wrote global chunk (cs ^ (row&7)) at slot cs,
// so global chunk q sits at slot q^(row&7). Returns ELEMENT offset.
DEV int swz(int row, int chunk) { return (chunk ^ (row & 7)) * 8; }

__global__ __launch_bounds__(256) void cvt_f32_f16(const float* __restrict__ src,
                                                   f16* __restrict__ dst, int n4) {
    int i = blockIdx.x * 256 + threadIdx.x;
    if (i >= n4) return;
    f32x4 v = *((const f32x4*)src + i);
    f16x4 o;
    o[0] = (f16)v[0]; o[1] = (f16)v[1]; o[2] = (f16)v[2]; o[3] = (f16)v[3];
    *((f16x4*)dst + i) = o;
}

// C[m][n] = sum_k A[m][k] * Bw[n][k];  A:(M,K) f16, Bw:(N,K) f16. 128x128 tile, BK=64.
template <bool F32OUT>
__global__ __launch_bounds__(256) void gemm_bt(const f16* __restrict__ A,
                                               const f16* __restrict__ Bw,
                                               void* __restrict__ Cout,
                                               int M, int N, int K) {
    __shared__ alignas(16) f16 As[128 * 64];
    __shared__ alignas(16) f16 Bs[128 * 64];
    const int tid = threadIdx.x;
    const int lane = tid & 63, w = tid >> 6;
    const int l15 = lane & 15, lg = lane >> 4;
    const int m0 = blockIdx.x * 128, n0 = blockIdx.y * 128;
    const int wr = (w >> 1) * 64, wc = (w & 1) * 64;
    f32x4 acc[4][4] = {};
    const int nk = K >> 6;

    auto stage = [&](int k0) {
#pragma unroll
        for (int it = 0; it < 4; ++it) {
            int idx = it * 256 + tid;
            int row = idx >> 3, cs = idx & 7;
            int gc = (cs ^ (row & 7)) * 8;
            gload16(A + (size_t)(m0 + row) * K + k0 + gc, (const char*)As + idx * 16);
            gload16(Bw + (size_t)(n0 + row) * K + k0 + gc, (const char*)Bs + idx * 16);
        }
    };
    stage(0);
    for (int kt = 0; kt < nk; ++kt) {
        __syncthreads();
#pragma unroll
        for (int kk = 0; kk < 2; ++kk) {
            f16x8 af[4], bfr[4];
#pragma unroll
            for (int i = 0; i < 4; ++i) {
                int ar = wr + i * 16 + l15;
                af[i] = *(const f16x8*)&As[ar * 64 + swz(ar, kk * 4 + lg)];
                int br = wc + i * 16 + l15;
                bfr[i] = *(const f16x8*)&Bs[br * 64 + swz(br, kk * 4 + lg)];
            }
#pragma unroll
            for (int i = 0; i < 4; ++i)
#pragma unroll
                for (int j = 0; j < 4; ++j)
                    acc[i][j] = mfma16(af[i], bfr[j], acc[i][j]);
        }
        __syncthreads();
        if (kt + 1 < nk) stage((kt + 1) << 6);
    }
#pragma unroll
    for (int i = 0; i < 4; ++i)
#pragma unroll
        for (int j = 0; j < 4; ++j)
#pragma unroll
            for (int r = 0; r < 4; ++r) {
                size_t rr = (size_t)(m0 + wr + i * 16 + lg * 4 + r);
                int cc = n0 + wc + j * 16 + l15;
                if constexpr (F32OUT) ((float*)Cout)[rr * (size_t)N + cc] = acc[i][j][r];
                else                  ((f16*)Cout)[rr * (size_t)N + cc]   = (f16)acc[i][j][r];
            }
}

// Fused RMSNorm + RoPE, f32 internal math; emits SPLIT fp16: hi + lo*32.
// One wave per 256-wide head vector; RoPE partner via shfl_xor(32).
__global__ __launch_bounds__(256) void norm_rope_split(const f16* __restrict__ in, int inStride, int inColOff,
                                                       f16* __restrict__ outH, f16* __restrict__ outL, int outStride,
                                                       const float* __restrict__ scale,
                                                       const float* __restrict__ cosT,
                                                       const float* __restrict__ sinT,
                                                       int hBits, float outScale, int nvec) {
    int vec = blockIdx.x * 4 + (threadIdx.x >> 6);
    if (vec >= nvec) return;
    const int lane = threadIdx.x & 63;
    const int row = vec >> hBits;
    const int h = vec & ((1 << hBits) - 1);
    const int s = row & 4095;
    const f16* p = in + (size_t)row * inStride + inColOff + h * 256 + lane * 4;
    f16x4 raw = *(const f16x4*)p;
    float f[4];
    float ss = 0.f;
#pragma unroll
    for (int i = 0; i < 4; ++i) { f[i] = (float)raw[i]; ss += f[i] * f[i]; }
#pragma unroll
    for (int off = 1; off < 64; off <<= 1) ss += __shfl_xor(ss, off, 64);
    const float inv = rsqrtf(ss * (1.0f / 256.0f) + 1e-6f);
    f32x4 sc4 = *(const f32x4*)(scale + lane * 4);
    float xn[4];
#pragma unroll
    for (int i = 0; i < 4; ++i) xn[i] = f[i] * inv * (1.0f + sc4[i]);
    f32x4 c4 = *(const f32x4*)(cosT + (size_t)s * 256 + lane * 4);
    f32x4 s4 = *(const f32x4*)(sinT + (size_t)s * 256 + lane * 4);
    f16x4 oh, ol;
#pragma unroll
    for (int i = 0; i < 4; ++i) {
        float pv = __shfl_xor(xn[i], 32, 64);
        float rot = (lane < 32) ? -pv : pv;
        float val = (xn[i] * c4[i] + rot * s4[i]) * outScale;
        f16 hi = (f16)val;
        oh[i] = hi;
        ol[i] = (f16)((val - (float)hi) * 32.0f);  // lo scaled x32: stays fp16-normal
    }
    size_t ob = (size_t)row * outStride + h * 256 + lane * 4;
    *(f16x4*)(outH + ob) = oh;
    *(f16x4*)(outL + ob) = ol;
}

// V slice of qkv (cols 1280..1535) -> vt[b][d][s]  (b:2, d:256, s:4096). Pure bit-moves.
__global__ __launch_bounds__(256) void transpose_v(const u16* __restrict__ qkv, u16* __restrict__ vt) {
    __shared__ u16 t[64][72];
    const int s0 = blockIdx.x * 64, d0 = blockIdx.y * 64, b = blockIdx.z;
#pragma unroll
    for (int i = 0; i < 16; ++i) {
        int idx = threadIdx.x + i * 256;
        int si = idx >> 6, di = idx & 63;
        t[si][di] = qkv[(size_t)(b * 4096 + s0 + si) * 1536 + 1280 + d0 + di];
    }
    __syncthreads();
#pragma unroll
    for (int i = 0; i < 16; ++i) {
        int idx = threadIdx.x + i * 256;
        int dj = idx >> 6, sj = idx & 63;
        vt[(size_t)b * (256 * 4096) + (size_t)(d0 + dj) * 4096 + (s0 + sj)] = t[sj][dj];
    }
}

// Causal flash attention, split-precision QK^T (q,k = hi + lo/32), P staged x64.
// Grid: (64 q-tiles reversed, H=4, B=2). 4 waves, QT=KT=64, HD=256.
__global__ __launch_bounds__(256) void attn(const f16* __restrict__ qhg, const f16* __restrict__ qlg,
                                            const f16* __restrict__ khg, const f16* __restrict__ klg,
                                            const f16* __restrict__ vtg,
                                            f16* __restrict__ ctx) {
    __shared__ alignas(16) f16 Kh[64 * 256];   // [kv][d] hi, XOR-swizzled chunks
    __shared__ alignas(16) f16 Kl[64 * 256];   // [kv][d] lo*32
    __shared__ alignas(16) f16 Vs[256 * 64];   // [d][kv]
    __shared__ alignas(16) f16 Ps[4][16 * 64]; // per-wave P*64, swizzled
    const int tid = threadIdx.x;
    const int lane = tid & 63, w = tid >> 6;
    const int l15 = lane & 15, lg = lane >> 4;
    const int qt = 63 - (int)blockIdx.x;       // heavy blocks dispatch first
    const int h = blockIdx.y, b = blockIdx.z;

    // Q fragments (hi+lo) in registers: 16 rows x 256 d per wave
    f16x8 qfh[8], qfl[8];
    {
        const size_t qoff = (size_t)(b * 4096 + qt * 64 + w * 16 + l15) * 1024 + h * 256 + lg * 8;
#pragma unroll
        for (int e = 0; e < 8; ++e) {
            qfh[e] = *(const f16x8*)(qhg + qoff + e * 32);
            qfl[e] = *(const f16x8*)(qlg + qoff + e * 32);
        }
    }
    f32x4 ao[16] = {};
    float m_[4] = {-3e38f, -3e38f, -3e38f, -3e38f};
    float l_[4] = {0.f, 0.f, 0.f, 0.f};
    const int nt = qt + 1;

    auto stageKV = [&](int t) {
#pragma unroll
        for (int it = 0; it < 8; ++it) {
            int idx = it * 256 + tid;
            {
                int r = idx >> 5, cs = idx & 31;
                int gc = (cs ^ (r & 7)) * 8;
                size_t src = (size_t)(b * 4096 + t * 64 + r) * 256 + gc;
                gload16(khg + src, (const char*)Kh + idx * 16);
                gload16(klg + src, (const char*)Kl + idx * 16);
            }
            {
                int r = idx >> 3, cs = idx & 7;
                int gc = (cs ^ (r & 7)) * 8;
                gload16(vtg + (size_t)b * (256 * 4096) + (size_t)r * 4096 + t * 64 + gc,
                        (const char*)Vs + idx * 16);
            }
        }
    };
    stageKV(0);
    for (int t = 0; t < nt; ++t) {
        __syncthreads();  // staging complete (compiler drains vmcnt before s_barrier)
        // ---- QK^T split: sc = qh*kh; s2 = qh*kl + ql*kh (both x32); total = sc + s2/32
        f32x4 sc[4] = {}, s2[4] = {};
#pragma unroll
        for (int c = 0; c < 4; ++c) {
            int krow = c * 16 + l15;
#pragma unroll
            for (int kk = 0; kk < 8; ++kk) {
                int o = krow * 256 + swz(krow, kk * 4 + lg);
                f16x8 kbh = *(const f16x8*)&Kh[o];
                f16x8 kbl = *(const f16x8*)&Kl[o];
                sc[c] = mfma16(qfh[kk], kbh, sc[c]);
                s2[c] = mfma16(qfh[kk], kbl, s2[c]);
                s2[c] = mfma16(qfl[kk], kbh, s2[c]);
            }
        }
#pragma unroll
        for (int c = 0; c < 4; ++c)
#pragma unroll
            for (int r = 0; r < 4; ++r)
                sc[c][r] = sc[c][r] + s2[c][r] * (1.0f / 32.0f);
        // ---- causal mask (diagonal tile only)
        if (t == qt) {
#pragma unroll
            for (int c = 0; c < 4; ++c)
#pragma unroll
                for (int r = 0; r < 4; ++r) {
                    int qi = w * 16 + lg * 4 + r;
                    int ki = c * 16 + l15;
                    if (ki > qi) sc[c][r] = -3e38f;
                }
        }
        // ---- online softmax (per 4 rows owned by this lane-group)
#pragma unroll
        for (int r = 0; r < 4; ++r) {
            float v = fmaxf(fmaxf(sc[0][r], sc[1][r]), fmaxf(sc[2][r], sc[3][r]));
            v = fmaxf(v, __shfl_xor(v, 1, 64));
            v = fmaxf(v, __shfl_xor(v, 2, 64));
            v = fmaxf(v, __shfl_xor(v, 4, 64));
            v = fmaxf(v, __shfl_xor(v, 8, 64));
            const float mn = fmaxf(m_[r], v);
            const float resc = __builtin_amdgcn_exp2f((m_[r] - mn) * 1.44269504f);
            m_[r] = mn;
            float rs = 0.f;
#pragma unroll
            for (int c = 0; c < 4; ++c) {
                float pp = __builtin_amdgcn_exp2f((sc[c][r] - mn) * 1.44269504f);
                sc[c][r] = pp;
                rs += pp;
            }
            rs += __shfl_xor(rs, 1, 64); rs += __shfl_xor(rs, 2, 64);
            rs += __shfl_xor(rs, 4, 64); rs += __shfl_xor(rs, 8, 64);
            l_[r] = l_[r] * resc + rs;
#pragma unroll
            for (int df = 0; df < 16; ++df) ao[df][r] *= resc;
        }
        // ---- P*64 -> LDS (swizzled; x64 keeps small P out of fp16 subnormal range)
#pragma unroll
        for (int c = 0; c < 4; ++c)
#pragma unroll
            for (int r = 0; r < 4; ++r) {
                int prow = lg * 4 + r;
                int chunk = c * 2 + (l15 >> 3);
                Ps[w][prow * 64 + ((chunk ^ (prow & 7)) * 8) + (l15 & 7)] = (f16)(sc[c][r] * 64.0f);
            }
        __syncthreads();
#pragma unroll
        for (int kk = 0; kk < 2; ++kk) {
            f16x8 pa = *(const f16x8*)&Ps[w][l15 * 64 + swz(l15, kk * 4 + lg)];
#pragma unroll
            for (int df = 0; df < 16; ++df) {
                int vrow = df * 16 + l15;
                f16x8 vb = *(const f16x8*)&Vs[vrow * 64 + swz(vrow, kk * 4 + lg)];
                ao[df] = mfma16(pa, vb, ao[df]);
            }
        }
        __syncthreads();  // all LDS reads done before restaging
        if (t + 1 < nt) stageKV(t + 1);
    }
    // ---- epilogue: ctx = ao / (64 * l)   (undo the P x64)
    float rl[4];
#pragma unroll
    for (int r = 0; r < 4; ++r) rl[r] = 1.0f / (l_[r] * 64.0f);
    const size_t orow0 = (size_t)(b * 4096 + qt * 64 + w * 16);
#pragma unroll
    for (int df = 0; df < 16; ++df)
#pragma unroll
        for (int r = 0; r < 4; ++r)
            ctx[(orow0 + lg * 4 + r) * 1024 + h * 256 + df * 16 + l15] = (f16)(ao[df][r] * rl[r]);
}

extern "C" void kernel_launch(void* const* d_in, const int* in_sizes, int n_in,
                              void* d_out, int out_size, void* d_ws, size_t ws_size,
                              hipStream_t stream) {
    (void)in_sizes; (void)n_in; (void)out_size; (void)ws_size;
    const float* x    = (const float*)d_in[0];
    const float* Wq   = (const float*)d_in[1];
    const float* Wk   = (const float*)d_in[2];
    const float* Wv   = (const float*)d_in[3];
    const float* Wo   = (const float*)d_in[4];
    const float* qsc  = (const float*)d_in[5];
    const float* ksc  = (const float*)d_in[6];
    const float* cosT = (const float*)d_in[7];
    const float* sinT = (const float*)d_in[8];
    // d_in[9] = mask: causal triu(k=1), structure known -> not read.

    // workspace layout (f16 elements), total ~102 MiB
    f16* xb   = (f16*)d_ws;                      // 8192*640
    f16* wcat = xb + (size_t)8192 * 640;         // 1536*640  (Wq | Wk | Wv rows)
    f16* wob  = wcat + (size_t)1536 * 640;       // 640*1024
    f16* qkv  = wob + (size_t)640 * 1024;        // 8192*1536 (q | k | v)
    f16* qh   = qkv + (size_t)8192 * 1536;       // 8192*1024
    f16* ql   = qh + (size_t)8192 * 1024;        // 8192*1024
    f16* kh   = ql + (size_t)8192 * 1024;        // 8192*256
    f16* kl   = kh + (size_t)8192 * 256;         // 8192*256
    f16* vt   = kl + (size_t)8192 * 256;         // 2*256*4096
    f16* ctxb = vt + (size_t)2 * 256 * 4096;     // 8192*1024

    // f32 -> f16 converts
    cvt_f32_f16<<<5120, 256, 0, stream>>>(x, xb, 1310720);
    cvt_f32_f16<<<640, 256, 0, stream>>>(Wq, wcat, 163840);
    cvt_f32_f16<<<160, 256, 0, stream>>>(Wk, wcat + 655360, 40960);
    cvt_f32_f16<<<160, 256, 0, stream>>>(Wv, wcat + 819200, 40960);
    cvt_f32_f16<<<640, 256, 0, stream>>>(Wo, wob, 163840);

    // fused QKV projection: (8192,640) x (1536,640)^T -> (8192,1536) f16
    gemm_bt<false><<<dim3(64, 12), 256, 0, stream>>>(xb, wcat, qkv, 8192, 1536, 640);

    // RMSNorm + RoPE, split hi/lo outputs; q gets the 1/16 scaling folded in
    norm_rope_split<<<8192, 256, 0, stream>>>(qkv, 1536, 0,    qh, ql, 1024, qsc, cosT, sinT, 2, 0.0625f, 32768);
    norm_rope_split<<<2048, 256, 0, stream>>>(qkv, 1536, 1024, kh, kl, 256,  ksc, cosT, sinT, 0, 1.0f,    8192);

    // V -> V^T for conflict-free PV B-fragments
    transpose_v<<<dim3(64, 4, 2), 256, 0, stream>>>((const u16*)qkv, (u16*)vt);

    // causal flash attention (split-precision scores)
    attn<<<dim3(64, 4, 2), 256, 0, stream>>>(qh, ql, kh, kl, vt, ctxb);

    // output projection: (8192,1024) x (640,1024)^T -> (8192,640) f32
    gemm_bt<true><<<dim3(64, 5), 256, 0, stream>>>(ctxb, wob, d_out, 8192, 640, 1024);
}

// Round 6
// 430.620 us; speedup vs baseline: 1.2754x; 1.2754x over previous
//
#include <hip/hip_runtime.h>

using u16 = unsigned short;
using f16 = _Float16;
typedef __attribute__((ext_vector_type(8))) _Float16 f16x8;
typedef __attribute__((ext_vector_type(4))) _Float16 f16x4;
typedef __attribute__((ext_vector_type(4))) float f32x4;

#define DEV static __device__ __forceinline__

// async global->LDS, 16B per lane. LDS dest must be wave-uniform base + lane*16.
DEV void gload16(const void* g, const void* l) {
    __builtin_amdgcn_global_load_lds((const __attribute__((address_space(1))) void*)g,
                                     (__attribute__((address_space(3))) void*)l,
                                     16, 0, 0);
}

DEV f32x4 mfma16(f16x8 a, f16x8 b, f32x4 c) {
    return __builtin_amdgcn_mfma_f32_16x16x32_f16(a, b, c, 0, 0, 0);
}

// 5-bit row-hash for 32-slot (512B) rows: spreads fragment reads to <=2-way.
DEV int g5(int R) { return ((R & 15) << 1) | ((R >> 4) & 1); }

__global__ __launch_bounds__(256) void cvt_f32_f16(const float* __restrict__ src,
                                                   f16* __restrict__ dst, int n4) {
    int i = blockIdx.x * 256 + threadIdx.x;
    if (i >= n4) return;
    f32x4 v = *((const f32x4*)src + i);
    f16x4 o;
    o[0] = (f16)v[0]; o[1] = (f16)v[1]; o[2] = (f16)v[2]; o[3] = (f16)v[3];
    *((f16x4*)dst + i) = o;
}

// C[m][n] = sum_k A[m][k]*Bw[n][k]. 128x128 tile, BK=64. LDS rows folded 2x ->
// [64 R][128 elems] (256B rows, 16 chunk slots) with 4-bit row-hash swizzle.
template <bool F32OUT>
__global__ __launch_bounds__(256) void gemm_bt(const f16* __restrict__ A,
                                               const f16* __restrict__ Bw,
                                               void* __restrict__ Cout,
                                               int M, int N, int K) {
    __shared__ alignas(16) f16 As[128 * 64];
    __shared__ alignas(16) f16 Bs[128 * 64];
    const int tid = threadIdx.x;
    const int lane = tid & 63, w = tid >> 6;
    const int l15 = lane & 15, lg = lane >> 4;
    const int m0 = blockIdx.x * 128, n0 = blockIdx.y * 128;
    const int wr = (w >> 1) * 64, wc = (w & 1) * 64;
    f32x4 acc[4][4] = {};
    const int nk = K >> 6;

    auto g4 = [](int R) { return ((R & 7) << 1) | ((R >> 3) & 1); };
    auto stage = [&](int k0) {
#pragma unroll
        for (int it = 0; it < 4; ++it) {
            int idx = it * 256 + tid;
            int R = idx >> 4, s = idx & 15;
            int c = s ^ (((R & 7) << 1) | ((R >> 3) & 1));
            int row = R * 2 + (c >> 3), kc = c & 7;
            gload16(A + (size_t)(m0 + row) * K + k0 + kc * 8, (const char*)As + idx * 16);
            gload16(Bw + (size_t)(n0 + row) * K + k0 + kc * 8, (const char*)Bs + idx * 16);
        }
    };
    stage(0);
    for (int kt = 0; kt < nk; ++kt) {
        __syncthreads();
#pragma unroll
        for (int kk = 0; kk < 2; ++kk) {
            f16x8 af[4], bfr[4];
#pragma unroll
            for (int i = 0; i < 4; ++i) {
                int ar = wr + i * 16 + l15;
                int Ra = ar >> 1;
                int sa = (((ar & 1) << 3) | (kk * 4 + lg)) ^ g4(Ra);
                af[i] = *(const f16x8*)&As[Ra * 128 + sa * 8];
                int br = wc + i * 16 + l15;
                int Rb = br >> 1;
                int sb = (((br & 1) << 3) | (kk * 4 + lg)) ^ g4(Rb);
                bfr[i] = *(const f16x8*)&Bs[Rb * 128 + sb * 8];
            }
#pragma unroll
            for (int i = 0; i < 4; ++i)
#pragma unroll
                for (int j = 0; j < 4; ++j)
                    acc[i][j] = mfma16(af[i], bfr[j], acc[i][j]);
        }
        __syncthreads();
        if (kt + 1 < nk) stage((kt + 1) << 6);
    }
#pragma unroll
    for (int i = 0; i < 4; ++i)
#pragma unroll
        for (int j = 0; j < 4; ++j)
#pragma unroll
            for (int r = 0; r < 4; ++r) {
                size_t rr = (size_t)(m0 + wr + i * 16 + lg * 4 + r);
                int cc = n0 + wc + j * 16 + l15;
                if constexpr (F32OUT) ((float*)Cout)[rr * (size_t)N + cc] = acc[i][j][r];
                else                  ((f16*)Cout)[rr * (size_t)N + cc]   = (f16)acc[i][j][r];
            }
}

// Fused RMSNorm + RoPE, f32 internal math; emits SPLIT fp16: hi + lo*32.
__global__ __launch_bounds__(256) void norm_rope_split(const f16* __restrict__ in, int inStride, int inColOff,
                                                       f16* __restrict__ outH, f16* __restrict__ outL, int outStride,
                                                       const float* __restrict__ scale,
                                                       const float* __restrict__ cosT,
                                                       const float* __restrict__ sinT,
                                                       int hBits, float outScale, int nvec) {
    int vec = blockIdx.x * 4 + (threadIdx.x >> 6);
    if (vec >= nvec) return;
    const int lane = threadIdx.x & 63;
    const int row = vec >> hBits;
    const int h = vec & ((1 << hBits) - 1);
    const int s = row & 4095;
    const f16* p = in + (size_t)row * inStride + inColOff + h * 256 + lane * 4;
    f16x4 raw = *(const f16x4*)p;
    float f[4];
    float ss = 0.f;
#pragma unroll
    for (int i = 0; i < 4; ++i) { f[i] = (float)raw[i]; ss += f[i] * f[i]; }
#pragma unroll
    for (int off = 1; off < 64; off <<= 1) ss += __shfl_xor(ss, off, 64);
    const float inv = rsqrtf(ss * (1.0f / 256.0f) + 1e-6f);
    f32x4 sc4 = *(const f32x4*)(scale + lane * 4);
    float xn[4];
#pragma unroll
    for (int i = 0; i < 4; ++i) xn[i] = f[i] * inv * (1.0f + sc4[i]);
    f32x4 c4 = *(const f32x4*)(cosT + (size_t)s * 256 + lane * 4);
    f32x4 s4 = *(const f32x4*)(sinT + (size_t)s * 256 + lane * 4);
    f16x4 oh, ol;
#pragma unroll
    for (int i = 0; i < 4; ++i) {
        float pv = __shfl_xor(xn[i], 32, 64);
        float rot = (lane < 32) ? -pv : pv;
        float val = (xn[i] * c4[i] + rot * s4[i]) * outScale;
        f16 hi = (f16)val;
        oh[i] = hi;
        ol[i] = (f16)((val - (float)hi) * 32.0f);
    }
    size_t ob = (size_t)row * outStride + h * 256 + lane * 4;
    *(f16x4*)(outH + ob) = oh;
    *(f16x4*)(outL + ob) = ol;
}

// V slice of qkv (cols 1280..1535) -> vt[b][d][s]
__global__ __launch_bounds__(256) void transpose_v(const u16* __restrict__ qkv, u16* __restrict__ vt) {
    __shared__ u16 t[64][72];
    const int s0 = blockIdx.x * 64, d0 = blockIdx.y * 64, b = blockIdx.z;
#pragma unroll
    for (int i = 0; i < 16; ++i) {
        int idx = threadIdx.x + i * 256;
        int si = idx >> 6, di = idx & 63;
        t[si][di] = qkv[(size_t)(b * 4096 + s0 + si) * 1536 + 1280 + d0 + di];
    }
    __syncthreads();
#pragma unroll
    for (int i = 0; i < 16; ++i) {
        int idx = threadIdx.x + i * 256;
        int dj = idx >> 6, sj = idx & 63;
        vt[(size_t)b * (256 * 4096) + (size_t)(d0 + dj) * 4096 + (s0 + sj)] = t[sj][dj];
    }
}

// Causal flash attention, split-precision QK^T, KVBLK=32, QBLK=64, 4 waves.
// LDS 52KB -> 2 blocks/CU (8 waves). Balanced (qt,h,b) <- blockIdx bit-mapping.
__global__ __launch_bounds__(256, 2) void attn(const f16* __restrict__ qhg, const f16* __restrict__ qlg,
                                               const f16* __restrict__ khg, const f16* __restrict__ klg,
                                               const f16* __restrict__ vtg,
                                               f16* __restrict__ ctx) {
    __shared__ alignas(16) f16 Kh[32 * 256];   // [kv][d], 32-slot rows, g5 swizzle
    __shared__ alignas(16) f16 Kl[32 * 256];
    __shared__ alignas(16) f16 Vs[32 * 256];   // [d>>3][(d&7)*4 + kv/8], g5 swizzle
    __shared__ alignas(16) f16 Ps[8 * 256];    // [qrow>>1][(qrow&1)*16 + w*4 + kv/8] ^ (R<<1)
    const int tid = threadIdx.x;
    const int lane = tid & 63, w = tid >> 6;
    const int l15 = lane & 15, lg = lane >> 4;

    // balanced work mapping: pairs id^1 / id^8 / id^256 have complementary cost
    const int id = blockIdx.x;
    const int x6 = ((id >> 1) & 3) | (((id >> 4) & 15) << 2);
    const int sel = (id ^ (id >> 3) ^ (id >> 8)) & 1;
    const int qt = sel ? 63 - x6 : x6;
    const int h = ((id >> 3) & 1) | (((id >> 8) & 1) << 1);
    const int b = id & 1;

    f16x8 qfh[8], qfl[8];
    {
        const size_t qoff = (size_t)(b * 4096 + qt * 64 + w * 16 + l15) * 1024 + h * 256 + lg * 8;
#pragma unroll
        for (int e = 0; e < 8; ++e) {
            qfh[e] = *(const f16x8*)(qhg + qoff + e * 32);
            qfl[e] = *(const f16x8*)(qlg + qoff + e * 32);
        }
    }
    f32x4 ao[16] = {};
    float m_[4] = {-3e38f, -3e38f, -3e38f, -3e38f};
    float l_[4] = {0.f, 0.f, 0.f, 0.f};
    const int nt = 2 * qt + 2;

    auto stageKV = [&](int t) {
#pragma unroll
        for (int it = 0; it < 4; ++it) {
            int idx = it * 256 + tid;
            int R = idx >> 5, s = idx & 31;
            int c = s ^ (((R & 15) << 1) | ((R >> 4) & 1));
            size_t ksrc = (size_t)(b * 4096 + t * 32 + R) * 256 + c * 8;
            gload16(khg + ksrc, (const char*)Kh + idx * 16);
            gload16(klg + ksrc, (const char*)Kl + idx * 16);
            int d = R * 8 + (c >> 2), kv0 = (c & 3) * 8;
            gload16(vtg + (size_t)b * 1048576 + (size_t)d * 4096 + t * 32 + kv0,
                    (const char*)Vs + idx * 16);
        }
    };
    stageKV(0);
    for (int t = 0; t < nt; ++t) {
        __syncthreads();  // staging complete
        // ---- QK^T split: sc = qh*kh; s2 = qh*kl + ql*kh; total = sc + s2/32
        f32x4 sc[2] = {}, s2[2] = {};
        __builtin_amdgcn_s_setprio(1);
#pragma unroll
        for (int cc = 0; cc < 2; ++cc) {
            int krow = cc * 16 + l15;
            int gk = g5(krow);
#pragma unroll
            for (int kk = 0; kk < 8; ++kk) {
                int o = krow * 256 + ((kk * 4 + lg) ^ gk) * 8;
                f16x8 kbh = *(const f16x8*)&Kh[o];
                f16x8 kbl = *(const f16x8*)&Kl[o];
                sc[cc] = mfma16(qfh[kk], kbh, sc[cc]);
                s2[cc] = mfma16(qfh[kk], kbl, s2[cc]);
                s2[cc] = mfma16(qfl[kk], kbh, s2[cc]);
            }
        }
        __builtin_amdgcn_s_setprio(0);
#pragma unroll
        for (int cc = 0; cc < 2; ++cc)
#pragma unroll
            for (int r = 0; r < 4; ++r)
                sc[cc][r] = sc[cc][r] + s2[cc][r] * (1.0f / 32.0f);
        // ---- causal mask (tiles overlapping the diagonal)
        if (t >= 2 * qt) {
#pragma unroll
            for (int cc = 0; cc < 2; ++cc)
#pragma unroll
                for (int r = 0; r < 4; ++r) {
                    int qi = qt * 64 + w * 16 + lg * 4 + r;
                    int ki = t * 32 + cc * 16 + l15;
                    if (ki > qi) sc[cc][r] = -3e38f;
                }
        }
        // ---- online softmax with defer-max (THR=4; P*64 <= 3494 < fp16 max)
        float vmax[4];
        bool need = false;
#pragma unroll
        for (int r = 0; r < 4; ++r) {
            float v = fmaxf(sc[0][r], sc[1][r]);
            v = fmaxf(v, __shfl_xor(v, 1, 64));
            v = fmaxf(v, __shfl_xor(v, 2, 64));
            v = fmaxf(v, __shfl_xor(v, 4, 64));
            v = fmaxf(v, __shfl_xor(v, 8, 64));
            vmax[r] = v;
            need = need || (v > m_[r] + 4.0f);
        }
        if (__any(need)) {
#pragma unroll
            for (int r = 0; r < 4; ++r) {
                float mn = fmaxf(m_[r], vmax[r]);
                float resc = __builtin_amdgcn_exp2f((m_[r] - mn) * 1.44269504f);
                m_[r] = mn;
                l_[r] *= resc;
#pragma unroll
                for (int df = 0; df < 16; ++df) ao[df][r] *= resc;
            }
        }
#pragma unroll
        for (int r = 0; r < 4; ++r) {
            float rs = 0.f;
#pragma unroll
            for (int cc = 0; cc < 2; ++cc) {
                float pp = __builtin_amdgcn_exp2f((sc[cc][r] - m_[r]) * 1.44269504f);
                sc[cc][r] = pp * 64.0f;
                rs += pp;
            }
            rs += __shfl_xor(rs, 1, 64); rs += __shfl_xor(rs, 2, 64);
            rs += __shfl_xor(rs, 4, 64); rs += __shfl_xor(rs, 8, 64);
            l_[r] += rs;
        }
        // ---- P*64 -> LDS (wave-private region; no barrier needed)
#pragma unroll
        for (int cc = 0; cc < 2; ++cc)
#pragma unroll
            for (int r = 0; r < 4; ++r) {
                int qrow = lg * 4 + r;
                int R = qrow >> 1;
                int chunk = ((qrow & 1) << 4) | (w << 2) | (cc * 2 + (l15 >> 3));
                int slot = chunk ^ (R << 1);
                Ps[R * 256 + slot * 8 + (l15 & 7)] = (f16)sc[cc][r];
            }
        // ---- PV
        {
            int Rp = l15 >> 1;
            int slotP = (((l15 & 1) << 4) | (w << 2) | lg) ^ (Rp << 1);
            f16x8 pa = *(const f16x8*)&Ps[Rp * 256 + slotP * 8];
            __builtin_amdgcn_s_setprio(1);
#pragma unroll
            for (int df = 0; df < 16; ++df) {
                int d = df * 16 + l15;
                int Rv = d >> 3;
                int slotV = ((((d & 7) << 2) | lg)) ^ g5(Rv);
                f16x8 vb = *(const f16x8*)&Vs[Rv * 256 + slotV * 8];
                ao[df] = mfma16(pa, vb, ao[df]);
            }
            __builtin_amdgcn_s_setprio(0);
        }
        __syncthreads();  // all LDS reads done before restaging
        if (t + 1 < nt) stageKV(t + 1);
    }
    // ---- epilogue: ctx = ao / (64 * l)
    float rl[4];
#pragma unroll
    for (int r = 0; r < 4; ++r) rl[r] = 1.0f / (l_[r] * 64.0f);
    const size_t orow0 = (size_t)(b * 4096 + qt * 64 + w * 16);
#pragma unroll
    for (int df = 0; df < 16; ++df)
#pragma unroll
        for (int r = 0; r < 4; ++r)
            ctx[(orow0 + lg * 4 + r) * 1024 + h * 256 + df * 16 + l15] = (f16)(ao[df][r] * rl[r]);
}

extern "C" void kernel_launch(void* const* d_in, const int* in_sizes, int n_in,
                              void* d_out, int out_size, void* d_ws, size_t ws_size,
                              hipStream_t stream) {
    (void)in_sizes; (void)n_in; (void)out_size; (void)ws_size;
    const float* x    = (const float*)d_in[0];
    const float* Wq   = (const float*)d_in[1];
    const float* Wk   = (const float*)d_in[2];
    const float* Wv   = (const float*)d_in[3];
    const float* Wo   = (const float*)d_in[4];
    const float* qsc  = (const float*)d_in[5];
    const float* ksc  = (const float*)d_in[6];
    const float* cosT = (const float*)d_in[7];
    const float* sinT = (const float*)d_in[8];

    f16* xb   = (f16*)d_ws;                      // 8192*640
    f16* wcat = xb + (size_t)8192 * 640;         // 1536*640
    f16* wob  = wcat + (size_t)1536 * 640;       // 640*1024
    f16* qkv  = wob + (size_t)640 * 1024;        // 8192*1536
    f16* qh   = qkv + (size_t)8192 * 1536;       // 8192*1024
    f16* ql   = qh + (size_t)8192 * 1024;        // 8192*1024
    f16* kh   = ql + (size_t)8192 * 1024;        // 8192*256
    f16* kl   = kh + (size_t)8192 * 256;         // 8192*256
    f16* vt   = kl + (size_t)8192 * 256;         // 2*256*4096
    f16* ctxb = vt + (size_t)2 * 256 * 4096;     // 8192*1024

    cvt_f32_f16<<<5120, 256, 0, stream>>>(x, xb, 1310720);
    cvt_f32_f16<<<640, 256, 0, stream>>>(Wq, wcat, 163840);
    cvt_f32_f16<<<160, 256, 0, stream>>>(Wk, wcat + 655360, 40960);
    cvt_f32_f16<<<160, 256, 0, stream>>>(Wv, wcat + 819200, 40960);
    cvt_f32_f16<<<640, 256, 0, stream>>>(Wo, wob, 163840);

    gemm_bt<false><<<dim3(64, 12), 256, 0, stream>>>(xb, wcat, qkv, 8192, 1536, 640);

    norm_rope_split<<<8192, 256, 0, stream>>>(qkv, 1536, 0,    qh, ql, 1024, qsc, cosT, sinT, 2, 0.0625f, 32768);
    norm_rope_split<<<2048, 256, 0, stream>>>(qkv, 1536, 1024, kh, kl, 256,  ksc, cosT, sinT, 0, 1.0f,    8192);

    transpose_v<<<dim3(64, 4, 2), 256, 0, stream>>>((const u16*)qkv, (u16*)vt);

    attn<<<512, 256, 0, stream>>>(qh, ql, kh, kl, vt, ctxb);

    gemm_bt<true><<<dim3(64, 5), 256, 0, stream>>>(ctxb, wob, d_out, 8192, 640, 1024);
}

// Round 7
// 262.601 us; speedup vs baseline: 2.0914x; 1.6398x over previous
//
#include <hip/hip_runtime.h>

using u16 = unsigned short;
using f16 = _Float16;
typedef __attribute__((ext_vector_type(8))) _Float16 f16x8;
typedef __attribute__((ext_vector_type(4))) _Float16 f16x4;
typedef __attribute__((ext_vector_type(4))) float f32x4;

#define DEV static __device__ __forceinline__

// async global->LDS, 16B per lane. LDS dest must be wave-uniform base + lane*16.
DEV void gload16(const void* g, const void* l) {
    __builtin_amdgcn_global_load_lds((const __attribute__((address_space(1))) void*)g,
                                     (__attribute__((address_space(3))) void*)l,
                                     16, 0, 0);
}

DEV f32x4 mfma16(f16x8 a, f16x8 b, f32x4 c) {
    return __builtin_amdgcn_mfma_f32_16x16x32_f16(a, b, c, 0, 0, 0);
}

// 5-bit row-hash for 32-slot (512B) rows: spreads fragment reads to <=2-way.
DEV int g5(int R) { return ((R & 15) << 1) | ((R >> 4) & 1); }

__global__ __launch_bounds__(256) void cvt_f32_f16(const float* __restrict__ src,
                                                   f16* __restrict__ dst, int n4) {
    int i = blockIdx.x * 256 + threadIdx.x;
    if (i >= n4) return;
    f32x4 v = *((const f32x4*)src + i);
    f16x4 o;
    o[0] = (f16)v[0]; o[1] = (f16)v[1]; o[2] = (f16)v[2]; o[3] = (f16)v[3];
    *((f16x4*)dst + i) = o;
}

// C[m][n] = sum_k A[m][k]*Bw[n][k]. 128x128 tile, BK=64. LDS rows folded 2x ->
// [64 R][128 elems] (256B rows, 16 chunk slots) with 4-bit row-hash swizzle.
template <bool F32OUT>
__global__ __launch_bounds__(256) void gemm_bt(const f16* __restrict__ A,
                                               const f16* __restrict__ Bw,
                                               void* __restrict__ Cout,
                                               int M, int N, int K) {
    __shared__ alignas(16) f16 As[128 * 64];
    __shared__ alignas(16) f16 Bs[128 * 64];
    const int tid = threadIdx.x;
    const int lane = tid & 63, w = tid >> 6;
    const int l15 = lane & 15, lg = lane >> 4;
    const int m0 = blockIdx.x * 128, n0 = blockIdx.y * 128;
    const int wr = (w >> 1) * 64, wc = (w & 1) * 64;
    f32x4 acc[4][4] = {};
    const int nk = K >> 6;

    auto g4 = [](int R) { return ((R & 7) << 1) | ((R >> 3) & 1); };
    auto stage = [&](int k0) {
#pragma unroll
        for (int it = 0; it < 4; ++it) {
            int idx = it * 256 + tid;
            int R = idx >> 4, s = idx & 15;
            int c = s ^ (((R & 7) << 1) | ((R >> 3) & 1));
            int row = R * 2 + (c >> 3), kc = c & 7;
            gload16(A + (size_t)(m0 + row) * K + k0 + kc * 8, (const char*)As + idx * 16);
            gload16(Bw + (size_t)(n0 + row) * K + k0 + kc * 8, (const char*)Bs + idx * 16);
        }
    };
    stage(0);
    for (int kt = 0; kt < nk; ++kt) {
        __syncthreads();
#pragma unroll
        for (int kk = 0; kk < 2; ++kk) {
            f16x8 af[4], bfr[4];
#pragma unroll
            for (int i = 0; i < 4; ++i) {
                int ar = wr + i * 16 + l15;
                int Ra = ar >> 1;
                int sa = (((ar & 1) << 3) | (kk * 4 + lg)) ^ g4(Ra);
                af[i] = *(const f16x8*)&As[Ra * 128 + sa * 8];
                int br = wc + i * 16 + l15;
                int Rb = br >> 1;
                int sb = (((br & 1) << 3) | (kk * 4 + lg)) ^ g4(Rb);
                bfr[i] = *(const f16x8*)&Bs[Rb * 128 + sb * 8];
            }
#pragma unroll
            for (int i = 0; i < 4; ++i)
#pragma unroll
                for (int j = 0; j < 4; ++j)
                    acc[i][j] = mfma16(af[i], bfr[j], acc[i][j]);
        }
        __syncthreads();
        if (kt + 1 < nk) stage((kt + 1) << 6);
    }
#pragma unroll
    for (int i = 0; i < 4; ++i)
#pragma unroll
        for (int j = 0; j < 4; ++j)
#pragma unroll
            for (int r = 0; r < 4; ++r) {
                size_t rr = (size_t)(m0 + wr + i * 16 + lg * 4 + r);
                int cc = n0 + wc + j * 16 + l15;
                if constexpr (F32OUT) ((float*)Cout)[rr * (size_t)N + cc] = acc[i][j][r];
                else                  ((f16*)Cout)[rr * (size_t)N + cc]   = (f16)acc[i][j][r];
            }
}

// Fused RMSNorm + RoPE, f32 internal math, fp16 out. outScale folds 1/16 and log2(e).
__global__ __launch_bounds__(256) void norm_rope(const f16* __restrict__ in, int inStride, int inColOff,
                                                 f16* __restrict__ out, int outStride,
                                                 const float* __restrict__ scale,
                                                 const float* __restrict__ cosT,
                                                 const float* __restrict__ sinT,
                                                 int hBits, float outScale, int nvec) {
    int vec = blockIdx.x * 4 + (threadIdx.x >> 6);
    if (vec >= nvec) return;
    const int lane = threadIdx.x & 63;
    const int row = vec >> hBits;
    const int h = vec & ((1 << hBits) - 1);
    const int s = row & 4095;
    const f16* p = in + (size_t)row * inStride + inColOff + h * 256 + lane * 4;
    f16x4 raw = *(const f16x4*)p;
    float f[4];
    float ss = 0.f;
#pragma unroll
    for (int i = 0; i < 4; ++i) { f[i] = (float)raw[i]; ss += f[i] * f[i]; }
#pragma unroll
    for (int off = 1; off < 64; off <<= 1) ss += __shfl_xor(ss, off, 64);
    const float inv = rsqrtf(ss * (1.0f / 256.0f) + 1e-6f);
    f32x4 sc4 = *(const f32x4*)(scale + lane * 4);
    float xn[4];
#pragma unroll
    for (int i = 0; i < 4; ++i) xn[i] = f[i] * inv * (1.0f + sc4[i]);
    f32x4 c4 = *(const f32x4*)(cosT + (size_t)s * 256 + lane * 4);
    f32x4 s4 = *(const f32x4*)(sinT + (size_t)s * 256 + lane * 4);
    f16x4 o;
#pragma unroll
    for (int i = 0; i < 4; ++i) {
        float pv = __shfl_xor(xn[i], 32, 64);
        float rot = (lane < 32) ? -pv : pv;
        o[i] = (f16)((xn[i] * c4[i] + rot * s4[i]) * outScale);
    }
    *(f16x4*)(out + (size_t)row * outStride + h * 256 + lane * 4) = o;
}

// V slice of qkv (cols 1280..1535) -> vt[b][d][s]
__global__ __launch_bounds__(256) void transpose_v(const u16* __restrict__ qkv, u16* __restrict__ vt) {
    __shared__ u16 t[64][72];
    const int s0 = blockIdx.x * 64, d0 = blockIdx.y * 64, b = blockIdx.z;
#pragma unroll
    for (int i = 0; i < 16; ++i) {
        int idx = threadIdx.x + i * 256;
        int si = idx >> 6, di = idx & 63;
        t[si][di] = qkv[(size_t)(b * 4096 + s0 + si) * 1536 + 1280 + d0 + di];
    }
    __syncthreads();
#pragma unroll
    for (int i = 0; i < 16; ++i) {
        int idx = threadIdx.x + i * 256;
        int dj = idx >> 6, sj = idx & 63;
        vt[(size_t)b * (256 * 4096) + (size_t)(d0 + dj) * 4096 + (s0 + sj)] = t[sj][dj];
    }
}

// Causal flash attention. KVBLK=32, QBLK=64, 4 waves, K/V double-buffered (T3 2-phase).
// Scores arrive in log2 domain (log2e folded into q). P staged as 2^(s-m+6) (=P*64).
// Rowsum via MFMA with ones-fragment (replaces shfl tree). LDS 68KB -> 2 blocks/CU.
__global__ __launch_bounds__(256, 2) void attn(const f16* __restrict__ qg,
                                               const f16* __restrict__ kg,
                                               const f16* __restrict__ vtg,
                                               f16* __restrict__ ctx) {
    __shared__ alignas(16) f16 Kh[2][32 * 256];  // [kv][d], 32-slot rows, g5 swizzle
    __shared__ alignas(16) f16 Vs[2][32 * 256];  // [d>>3][(d&7)*4 + kv/8], g5 swizzle
    __shared__ alignas(16) f16 Ps[8 * 256];      // per-wave P, swizzled
    const int tid = threadIdx.x;
    const int lane = tid & 63, w = tid >> 6;
    const int l15 = lane & 15, lg = lane >> 4;

    // balanced work mapping: pairs id^1 / id^8 / id^256 have complementary cost
    const int id = blockIdx.x;
    const int x6 = ((id >> 1) & 3) | (((id >> 4) & 15) << 2);
    const int sel = (id ^ (id >> 3) ^ (id >> 8)) & 1;
    const int qt = sel ? 63 - x6 : x6;
    const int h = ((id >> 3) & 1) | (((id >> 8) & 1) << 1);
    const int b = id & 1;

    f16x8 qf[8];
    {
        const size_t qoff = (size_t)(b * 4096 + qt * 64 + w * 16 + l15) * 1024 + h * 256 + lg * 8;
#pragma unroll
        for (int e = 0; e < 8; ++e) qf[e] = *(const f16x8*)(qg + qoff + e * 32);
    }
    f16x8 ones1;
#pragma unroll
    for (int e = 0; e < 8; ++e) ones1[e] = (f16)1.0f;

    f32x4 ao[16] = {};
    float m_[4] = {-3e38f, -3e38f, -3e38f, -3e38f};
    float l_[4] = {0.f, 0.f, 0.f, 0.f};
    const int nt = 2 * qt + 2;

    auto stageKV = [&](int t, int pb) {
#pragma unroll
        for (int it = 0; it < 4; ++it) {
            int idx = it * 256 + tid;
            int R = idx >> 5, s = idx & 31;
            int c = s ^ g5(R);
            size_t ksrc = (size_t)(b * 4096 + t * 32 + R) * 256 + c * 8;
            gload16(kg + ksrc, (const char*)&Kh[pb][0] + idx * 16);
            int d = R * 8 + (c >> 2), kv0 = (c & 3) * 8;
            gload16(vtg + (size_t)b * 1048576 + (size_t)d * 4096 + t * 32 + kv0,
                    (const char*)&Vs[pb][0] + idx * 16);
        }
    };
    stageKV(0, 0);
    __syncthreads();
    for (int t = 0; t < nt; ++t) {
        const int cur = t & 1;
        if (t + 1 < nt) stageKV(t + 1, cur ^ 1);   // issue early; hidden under compute
        // ---- QK^T (scores in log2 domain)
        f32x4 sc[2] = {};
        const f16* Kc = &Kh[cur][0];
        __builtin_amdgcn_s_setprio(1);
#pragma unroll
        for (int cc = 0; cc < 2; ++cc) {
            int krow = cc * 16 + l15;
            int gk = g5(krow);
#pragma unroll
            for (int kk = 0; kk < 8; ++kk) {
                f16x8 kb = *(const f16x8*)&Kc[krow * 256 + ((kk * 4 + lg) ^ gk) * 8];
                sc[cc] = mfma16(qf[kk], kb, sc[cc]);
            }
        }
        __builtin_amdgcn_s_setprio(0);
        // ---- causal mask (tiles overlapping the diagonal)
        if (t >= 2 * qt) {
#pragma unroll
            for (int cc = 0; cc < 2; ++cc)
#pragma unroll
                for (int r = 0; r < 4; ++r) {
                    int qi = qt * 64 + w * 16 + lg * 4 + r;
                    int ki = t * 32 + cc * 16 + l15;
                    if (ki > qi) sc[cc][r] = -3e38f;
                }
        }
        // ---- defer-max (T13): lane-local test first; reduce+rescale only if needed
        bool need = false;
        float vl[4];
#pragma unroll
        for (int r = 0; r < 4; ++r) {
            vl[r] = fmaxf(sc[0][r], sc[1][r]);
            need = need || (vl[r] > m_[r] + 5.0f);   // log2 units; P <= 2^11 < fp16 max
        }
        if (__any(need)) {
#pragma unroll
            for (int r = 0; r < 4; ++r) {
                float v = vl[r];
                v = fmaxf(v, __shfl_xor(v, 1, 64));
                v = fmaxf(v, __shfl_xor(v, 2, 64));
                v = fmaxf(v, __shfl_xor(v, 4, 64));
                v = fmaxf(v, __shfl_xor(v, 8, 64));
                float mn = fmaxf(m_[r], v);
                float resc = __builtin_amdgcn_exp2f(m_[r] - mn);
                m_[r] = mn;
                l_[r] *= resc;
#pragma unroll
                for (int df = 0; df < 16; ++df) ao[df][r] *= resc;
            }
        }
        // ---- P = 2^(sc - m + 6) -> LDS (wave-private region)
#pragma unroll
        for (int cc = 0; cc < 2; ++cc)
#pragma unroll
            for (int r = 0; r < 4; ++r) {
                float pp = __builtin_amdgcn_exp2f(sc[cc][r] - m_[r] + 6.0f);
                int qrow = lg * 4 + r;
                int R = qrow >> 1;
                int chunk = ((qrow & 1) << 4) | (w << 2) | (cc * 2 + (l15 >> 3));
                Ps[R * 256 + ((chunk ^ (R << 1))) * 8 + (l15 & 7)] = (f16)pp;
            }
        // ---- PV + MFMA rowsum
        {
            int Rp = l15 >> 1;
            int slotP = (((l15 & 1) << 4) | (w << 2) | lg) ^ (Rp << 1);
            f16x8 pa = *(const f16x8*)&Ps[Rp * 256 + slotP * 8];
            f32x4 zero = {0.f, 0.f, 0.f, 0.f};
            f32x4 rs4 = mfma16(pa, ones1, zero);   // row-sums of P for this tile
            const f16* Vc = &Vs[cur][0];
            __builtin_amdgcn_s_setprio(1);
#pragma unroll
            for (int df = 0; df < 16; ++df) {
                int d = df * 16 + l15;
                int Rv = d >> 3;
                int slotV = ((((d & 7) << 2) | lg)) ^ g5(Rv);
                f16x8 vb = *(const f16x8*)&Vc[Rv * 256 + slotV * 8];
                ao[df] = mfma16(pa, vb, ao[df]);
            }
            __builtin_amdgcn_s_setprio(0);
#pragma unroll
            for (int r = 0; r < 4; ++r) l_[r] += rs4[r];
        }
        __syncthreads();   // drains vmcnt(0): stage(t+1) landed; LDS reads done
    }
    // ---- epilogue: ctx = ao / l  (both in x64 domain)
    float rl[4];
#pragma unroll
    for (int r = 0; r < 4; ++r) rl[r] = 1.0f / l_[r];
    const size_t orow0 = (size_t)(b * 4096 + qt * 64 + w * 16);
#pragma unroll
    for (int df = 0; df < 16; ++df)
#pragma unroll
        for (int r = 0; r < 4; ++r)
            ctx[(orow0 + lg * 4 + r) * 1024 + h * 256 + df * 16 + l15] = (f16)(ao[df][r] * rl[r]);
}

extern "C" void kernel_launch(void* const* d_in, const int* in_sizes, int n_in,
                              void* d_out, int out_size, void* d_ws, size_t ws_size,
                              hipStream_t stream) {
    (void)in_sizes; (void)n_in; (void)out_size; (void)ws_size;
    const float* x    = (const float*)d_in[0];
    const float* Wq   = (const float*)d_in[1];
    const float* Wk   = (const float*)d_in[2];
    const float* Wv   = (const float*)d_in[3];
    const float* Wo   = (const float*)d_in[4];
    const float* qsc  = (const float*)d_in[5];
    const float* ksc  = (const float*)d_in[6];
    const float* cosT = (const float*)d_in[7];
    const float* sinT = (const float*)d_in[8];

    f16* xb   = (f16*)d_ws;                      // 8192*640
    f16* wcat = xb + (size_t)8192 * 640;         // 1536*640
    f16* wob  = wcat + (size_t)1536 * 640;       // 640*1024
    f16* qkv  = wob + (size_t)640 * 1024;        // 8192*1536
    f16* qh   = qkv + (size_t)8192 * 1536;       // 8192*1024
    f16* kh   = qh + (size_t)8192 * 1024;        // 8192*256
    f16* vt   = kh + (size_t)8192 * 256;         // 2*256*4096
    f16* ctxb = vt + (size_t)2 * 256 * 4096;     // 8192*1024

    cvt_f32_f16<<<5120, 256, 0, stream>>>(x, xb, 1310720);
    cvt_f32_f16<<<640, 256, 0, stream>>>(Wq, wcat, 163840);
    cvt_f32_f16<<<160, 256, 0, stream>>>(Wk, wcat + 655360, 40960);
    cvt_f32_f16<<<160, 256, 0, stream>>>(Wv, wcat + 819200, 40960);
    cvt_f32_f16<<<640, 256, 0, stream>>>(Wo, wob, 163840);

    gemm_bt<false><<<dim3(64, 12), 256, 0, stream>>>(xb, wcat, qkv, 8192, 1536, 640);

    // q gets 1/16 scaling AND log2(e) folded in (scores computed in log2 domain)
    norm_rope<<<8192, 256, 0, stream>>>(qkv, 1536, 0,    qh, 1024, qsc, cosT, sinT, 2,
                                        0.0625f * 1.44269504f, 32768);
    norm_rope<<<2048, 256, 0, stream>>>(qkv, 1536, 1024, kh, 256,  ksc, cosT, sinT, 0,
                                        1.0f, 8192);

    transpose_v<<<dim3(64, 4, 2), 256, 0, stream>>>((const u16*)qkv, (u16*)vt);

    attn<<<512, 256, 0, stream>>>(qh, kh, vt, ctxb);

    gemm_bt<true><<<dim3(64, 5), 256, 0, stream>>>(ctxb, wob, d_out, 8192, 640, 1024);
}

// Round 8
// 204.811 us; speedup vs baseline: 2.6815x; 1.2822x over previous
//
#include <hip/hip_runtime.h>

using u16 = unsigned short;
using f16 = _Float16;
typedef __attribute__((ext_vector_type(8))) _Float16 f16x8;
typedef __attribute__((ext_vector_type(4))) _Float16 f16x4;
typedef __attribute__((ext_vector_type(4))) float f32x4;

#define DEV static __device__ __forceinline__

// async global->LDS, 16B per lane. LDS dest must be wave-uniform base + lane*16.
DEV void gload16(const void* g, const void* l) {
    __builtin_amdgcn_global_load_lds((const __attribute__((address_space(1))) void*)g,
                                     (__attribute__((address_space(3))) void*)l,
                                     16, 0, 0);
}

DEV f32x4 mfma16(f16x8 a, f16x8 b, f32x4 c) {
    return __builtin_amdgcn_mfma_f32_16x16x32_f16(a, b, c, 0, 0, 0);
}

// 5-bit row-hash for 32-slot (512B) rows: spreads fragment reads to <=2-way.
DEV int g5(int R) { return ((R & 15) << 1) | ((R >> 4) & 1); }

__global__ __launch_bounds__(256) void cvt_f32_f16(const float* __restrict__ src,
                                                   f16* __restrict__ dst, int n4) {
    int i = blockIdx.x * 256 + threadIdx.x;
    if (i >= n4) return;
    f32x4 v = *((const f32x4*)src + i);
    f16x4 o;
    o[0] = (f16)v[0]; o[1] = (f16)v[1]; o[2] = (f16)v[2]; o[3] = (f16)v[3];
    *((f16x4*)dst + i) = o;
}

// C[m][n] = sum_k A[m][k]*Bw[n][k]. 128x128 tile, BK=64. LDS rows folded 2x ->
// [64 R][128 elems] (256B rows, 16 chunk slots) with 4-bit row-hash swizzle.
template <bool F32OUT>
__global__ __launch_bounds__(256) void gemm_bt(const f16* __restrict__ A,
                                               const f16* __restrict__ Bw,
                                               void* __restrict__ Cout,
                                               int M, int N, int K) {
    __shared__ alignas(16) f16 As[128 * 64];
    __shared__ alignas(16) f16 Bs[128 * 64];
    const int tid = threadIdx.x;
    const int lane = tid & 63, w = tid >> 6;
    const int l15 = lane & 15, lg = lane >> 4;
    const int m0 = blockIdx.x * 128, n0 = blockIdx.y * 128;
    const int wr = (w >> 1) * 64, wc = (w & 1) * 64;
    f32x4 acc[4][4] = {};
    const int nk = K >> 6;

    auto g4 = [](int R) { return ((R & 7) << 1) | ((R >> 3) & 1); };
    auto stage = [&](int k0) {
#pragma unroll
        for (int it = 0; it < 4; ++it) {
            int idx = it * 256 + tid;
            int R = idx >> 4, s = idx & 15;
            int c = s ^ (((R & 7) << 1) | ((R >> 3) & 1));
            int row = R * 2 + (c >> 3), kc = c & 7;
            gload16(A + (size_t)(m0 + row) * K + k0 + kc * 8, (const char*)As + idx * 16);
            gload16(Bw + (size_t)(n0 + row) * K + k0 + kc * 8, (const char*)Bs + idx * 16);
        }
    };
    stage(0);
    for (int kt = 0; kt < nk; ++kt) {
        __syncthreads();
#pragma unroll
        for (int kk = 0; kk < 2; ++kk) {
            f16x8 af[4], bfr[4];
#pragma unroll
            for (int i = 0; i < 4; ++i) {
                int ar = wr + i * 16 + l15;
                int Ra = ar >> 1;
                int sa = (((ar & 1) << 3) | (kk * 4 + lg)) ^ g4(Ra);
                af[i] = *(const f16x8*)&As[Ra * 128 + sa * 8];
                int br = wc + i * 16 + l15;
                int Rb = br >> 1;
                int sb = (((br & 1) << 3) | (kk * 4 + lg)) ^ g4(Rb);
                bfr[i] = *(const f16x8*)&Bs[Rb * 128 + sb * 8];
            }
#pragma unroll
            for (int i = 0; i < 4; ++i)
#pragma unroll
                for (int j = 0; j < 4; ++j)
                    acc[i][j] = mfma16(af[i], bfr[j], acc[i][j]);
        }
        __syncthreads();
        if (kt + 1 < nk) stage((kt + 1) << 6);
    }
#pragma unroll
    for (int i = 0; i < 4; ++i)
#pragma unroll
        for (int j = 0; j < 4; ++j)
#pragma unroll
            for (int r = 0; r < 4; ++r) {
                size_t rr = (size_t)(m0 + wr + i * 16 + lg * 4 + r);
                int cc = n0 + wc + j * 16 + l15;
                if constexpr (F32OUT) ((float*)Cout)[rr * (size_t)N + cc] = acc[i][j][r];
                else                  ((f16*)Cout)[rr * (size_t)N + cc]   = (f16)acc[i][j][r];
            }
}

// Fused RMSNorm + RoPE, f32 internal math, fp16 out. outScale folds 1/16 and log2(e).
__global__ __launch_bounds__(256) void norm_rope(const f16* __restrict__ in, int inStride, int inColOff,
                                                 f16* __restrict__ out, int outStride,
                                                 const float* __restrict__ scale,
                                                 const float* __restrict__ cosT,
                                                 const float* __restrict__ sinT,
                                                 int hBits, float outScale, int nvec) {
    int vec = blockIdx.x * 4 + (threadIdx.x >> 6);
    if (vec >= nvec) return;
    const int lane = threadIdx.x & 63;
    const int row = vec >> hBits;
    const int h = vec & ((1 << hBits) - 1);
    const int s = row & 4095;
    const f16* p = in + (size_t)row * inStride + inColOff + h * 256 + lane * 4;
    f16x4 raw = *(const f16x4*)p;
    float f[4];
    float ss = 0.f;
#pragma unroll
    for (int i = 0; i < 4; ++i) { f[i] = (float)raw[i]; ss += f[i] * f[i]; }
#pragma unroll
    for (int off = 1; off < 64; off <<= 1) ss += __shfl_xor(ss, off, 64);
    const float inv = rsqrtf(ss * (1.0f / 256.0f) + 1e-6f);
    f32x4 sc4 = *(const f32x4*)(scale + lane * 4);
    float xn[4];
#pragma unroll
    for (int i = 0; i < 4; ++i) xn[i] = f[i] * inv * (1.0f + sc4[i]);
    f32x4 c4 = *(const f32x4*)(cosT + (size_t)s * 256 + lane * 4);
    f32x4 s4 = *(const f32x4*)(sinT + (size_t)s * 256 + lane * 4);
    f16x4 o;
#pragma unroll
    for (int i = 0; i < 4; ++i) {
        float pv = __shfl_xor(xn[i], 32, 64);
        float rot = (lane < 32) ? -pv : pv;
        o[i] = (f16)((xn[i] * c4[i] + rot * s4[i]) * outScale);
    }
    *(f16x4*)(out + (size_t)row * outStride + h * 256 + lane * 4) = o;
}

// V slice of qkv (cols 1280..1535) -> vt[b][d][s]
__global__ __launch_bounds__(256) void transpose_v(const u16* __restrict__ qkv, u16* __restrict__ vt) {
    __shared__ u16 t[64][72];
    const int s0 = blockIdx.x * 64, d0 = blockIdx.y * 64, b = blockIdx.z;
#pragma unroll
    for (int i = 0; i < 16; ++i) {
        int idx = threadIdx.x + i * 256;
        int si = idx >> 6, di = idx & 63;
        t[si][di] = qkv[(size_t)(b * 4096 + s0 + si) * 1536 + 1280 + d0 + di];
    }
    __syncthreads();
#pragma unroll
    for (int i = 0; i < 16; ++i) {
        int idx = threadIdx.x + i * 256;
        int dj = idx >> 6, sj = idx & 63;
        vt[(size_t)b * (256 * 4096) + (size_t)(d0 + dj) * 4096 + (s0 + sj)] = t[sj][dj];
    }
}

// Causal flash attention, split-K over kv parity. Each block: one (b,h,qt,par),
// processes kv-32-tiles t = par, par+2, ..., par+2*qt  (exactly qt+1 tiles).
// Writes NORMALIZED partial (ao/l as f16) + (m,l as f32); merge kernel combines.
// blockIdx ascending = cost descending (LPT); queue refill smooths the tail.
__global__ __launch_bounds__(256, 2) void attn(const f16* __restrict__ qg,
                                               const f16* __restrict__ kg,
                                               const f16* __restrict__ vtg,
                                               f16* __restrict__ pao,
                                               float* __restrict__ pml) {
    __shared__ alignas(16) f16 Kh[2][32 * 256];  // [kv][d], 32-slot rows, g5 swizzle
    __shared__ alignas(16) f16 Vs[2][32 * 256];  // [d>>3][(d&7)*4 + kv/8], g5 swizzle
    __shared__ alignas(16) f16 Ps[8 * 256];      // per-wave P, swizzled
    const int tid = threadIdx.x;
    const int lane = tid & 63, w = tid >> 6;
    const int l15 = lane & 15, lg = lane >> 4;

    const int id = blockIdx.x;
    const int qt  = 63 - (id >> 4);      // big q-tiles dispatch first (LPT)
    const int par = (id >> 3) & 1;       // kv parity; (id, id+8) share K/V stream
    const int h   = (id >> 1) & 3;
    const int b   = id & 1;

    f16x8 qf[8];
    {
        const size_t qoff = (size_t)(b * 4096 + qt * 64 + w * 16 + l15) * 1024 + h * 256 + lg * 8;
#pragma unroll
        for (int e = 0; e < 8; ++e) qf[e] = *(const f16x8*)(qg + qoff + e * 32);
    }
    f16x8 ones1;
#pragma unroll
    for (int e = 0; e < 8; ++e) ones1[e] = (f16)1.0f;

    f32x4 ao[16] = {};
    float m_[4] = {-3e38f, -3e38f, -3e38f, -3e38f};
    float l_[4] = {0.f, 0.f, 0.f, 0.f};
    const int nt = qt + 1;

    auto stageKV = [&](int t, int pb) {
#pragma unroll
        for (int it = 0; it < 4; ++it) {
            int idx = it * 256 + tid;
            int R = idx >> 5, s = idx & 31;
            int c = s ^ g5(R);
            size_t ksrc = (size_t)(b * 4096 + t * 32 + R) * 256 + c * 8;
            gload16(kg + ksrc, (const char*)&Kh[pb][0] + idx * 16);
            int d = R * 8 + (c >> 2), kv0 = (c & 3) * 8;
            gload16(vtg + (size_t)b * 1048576 + (size_t)d * 4096 + t * 32 + kv0,
                    (const char*)&Vs[pb][0] + idx * 16);
        }
    };
    stageKV(par, 0);
    for (int i = 0; i < nt; ++i) {
        const int cur = i & 1;
        const int t = par + 2 * i;
        __syncthreads();                       // tile i staged (all waves); prev reads done
        if (i + 1 < nt) stageKV(t + 2, cur ^ 1);   // prefetch; drains at NEXT sync
        // ---- QK^T (scores in log2 domain), 4 independent MFMA chains
        f32x4 sa[2] = {}, sb[2] = {};
        const f16* Kc = &Kh[cur][0];
        __builtin_amdgcn_s_setprio(1);
#pragma unroll
        for (int cc = 0; cc < 2; ++cc) {
            int krow = cc * 16 + l15;
            int gk = g5(krow);
#pragma unroll
            for (int kk = 0; kk < 4; ++kk) {
                f16x8 kb0 = *(const f16x8*)&Kc[krow * 256 + (((2 * kk) * 4 + lg) ^ gk) * 8];
                f16x8 kb1 = *(const f16x8*)&Kc[krow * 256 + (((2 * kk + 1) * 4 + lg) ^ gk) * 8];
                sa[cc] = mfma16(qf[2 * kk], kb0, sa[cc]);
                sb[cc] = mfma16(qf[2 * kk + 1], kb1, sb[cc]);
            }
        }
        __builtin_amdgcn_s_setprio(0);
        f32x4 sc[2];
#pragma unroll
        for (int cc = 0; cc < 2; ++cc)
#pragma unroll
            for (int r = 0; r < 4; ++r)
                sc[cc][r] = sa[cc][r] + sb[cc][r];
        // ---- causal mask (only the last tile of each parity touches the diagonal)
        if (i == qt) {
#pragma unroll
            for (int cc = 0; cc < 2; ++cc)
#pragma unroll
                for (int r = 0; r < 4; ++r) {
                    int qi = qt * 64 + w * 16 + lg * 4 + r;
                    int ki = t * 32 + cc * 16 + l15;
                    if (ki > qi) sc[cc][r] = -3e38f;
                }
        }
        // ---- defer-max (T13): lane-local test; reduce+rescale only if needed
        bool need = false;
        float vl[4];
#pragma unroll
        for (int r = 0; r < 4; ++r) {
            vl[r] = fmaxf(sc[0][r], sc[1][r]);
            need = need || (vl[r] > m_[r] + 5.0f);   // log2 units; P <= 2^11 < fp16 max
        }
        if (__any(need)) {
#pragma unroll
            for (int r = 0; r < 4; ++r) {
                float v = vl[r];
                v = fmaxf(v, __shfl_xor(v, 1, 64));
                v = fmaxf(v, __shfl_xor(v, 2, 64));
                v = fmaxf(v, __shfl_xor(v, 4, 64));
                v = fmaxf(v, __shfl_xor(v, 8, 64));
                float mn = fmaxf(m_[r], v);
                float resc = __builtin_amdgcn_exp2f(m_[r] - mn);
                m_[r] = mn;
                l_[r] *= resc;
#pragma unroll
                for (int df = 0; df < 16; ++df) ao[df][r] *= resc;
            }
        }
        // ---- P = 2^(sc - m + 6) -> LDS (wave-private region)
#pragma unroll
        for (int cc = 0; cc < 2; ++cc)
#pragma unroll
            for (int r = 0; r < 4; ++r) {
                float pp = __builtin_amdgcn_exp2f(sc[cc][r] - m_[r] + 6.0f);
                int qrow = lg * 4 + r;
                int R = qrow >> 1;
                int chunk = ((qrow & 1) << 4) | (w << 2) | (cc * 2 + (l15 >> 3));
                Ps[R * 256 + ((chunk ^ (R << 1))) * 8 + (l15 & 7)] = (f16)pp;
            }
        // ---- PV + MFMA rowsum
        {
            int Rp = l15 >> 1;
            int slotP = (((l15 & 1) << 4) | (w << 2) | lg) ^ (Rp << 1);
            f16x8 pa = *(const f16x8*)&Ps[Rp * 256 + slotP * 8];
            f32x4 zero = {0.f, 0.f, 0.f, 0.f};
            f32x4 rs4 = mfma16(pa, ones1, zero);   // row-sums of P for this tile
            const f16* Vc = &Vs[cur][0];
            __builtin_amdgcn_s_setprio(1);
#pragma unroll
            for (int df = 0; df < 16; ++df) {
                int d = df * 16 + l15;
                int Rv = d >> 3;
                int slotV = ((((d & 7) << 2) | lg)) ^ g5(Rv);
                f16x8 vb = *(const f16x8*)&Vc[Rv * 256 + slotV * 8];
                ao[df] = mfma16(pa, vb, ao[df]);
            }
            __builtin_amdgcn_s_setprio(0);
#pragma unroll
            for (int r = 0; r < 4; ++r) l_[r] += rs4[r];
        }
    }
    // ---- epilogue: write normalized partial ao/l (f16) + m,l (f32)
    float rl[4];
#pragma unroll
    for (int r = 0; r < 4; ++r) rl[r] = 1.0f / l_[r];
    const int p = ((b * 4 + h) * 64 + qt) * 2 + par;
    f16* aoP = pao + ((size_t)p * 64 + w * 16) * 256;
#pragma unroll
    for (int df = 0; df < 16; ++df)
#pragma unroll
        for (int r = 0; r < 4; ++r)
            aoP[(lg * 4 + r) * 256 + df * 16 + l15] = (f16)(ao[df][r] * rl[r]);
    if (l15 == 0) {
#pragma unroll
        for (int r = 0; r < 4; ++r) {
            int row = w * 16 + lg * 4 + r;
            pml[(size_t)p * 128 + row] = m_[r];
            pml[(size_t)p * 128 + 64 + row] = l_[r];
        }
    }
}

// Merge the two kv-parity partials per q-tile:
// out = (aoE*zE + aoO*zO) / (zE+zO),  z_p = l_p * 2^(m_p - M).
__global__ __launch_bounds__(256) void merge_partials(const f16* __restrict__ pao,
                                                      const float* __restrict__ pml,
                                                      f16* __restrict__ ctx) {
    const int p0 = blockIdx.x;            // (b*4+h)*64 + qt
    const int tid = threadIdx.x;
    const int row = tid >> 2;
    const int dl = (tid & 3) * 8;
    const int b = p0 >> 8, h = (p0 >> 6) & 3, qt = p0 & 63;
    const float* mlE = pml + (size_t)(2 * p0) * 128;
    float mE = mlE[row],       lE = mlE[64 + row];
    float mO = mlE[128 + row], lO = mlE[192 + row];
    float M = fmaxf(mE, mO);
    float zE = lE * exp2f(mE - M);
    float zO = lO * exp2f(mO - M);
    float rs = 1.0f / (zE + zO);
    float wE = zE * rs, wO = zO * rs;
    const f16* aE = pao + ((size_t)(2 * p0) * 64 + row) * 256 + dl;
    const f16* aO = aE + 64 * 256;
    f16* outp = ctx + (size_t)(b * 4096 + qt * 64 + row) * 1024 + h * 256 + dl;
#pragma unroll
    for (int c = 0; c < 8; ++c) {
        f16x8 e = *(const f16x8*)(aE + c * 32);
        f16x8 o = *(const f16x8*)(aO + c * 32);
        f16x8 ot;
#pragma unroll
        for (int j = 0; j < 8; ++j) ot[j] = (f16)((float)e[j] * wE + (float)o[j] * wO);
        *(f16x8*)(outp + c * 32) = ot;
    }
}

extern "C" void kernel_launch(void* const* d_in, const int* in_sizes, int n_in,
                              void* d_out, int out_size, void* d_ws, size_t ws_size,
                              hipStream_t stream) {
    (void)in_sizes; (void)n_in; (void)out_size; (void)ws_size;
    const float* x    = (const float*)d_in[0];
    const float* Wq   = (const float*)d_in[1];
    const float* Wk   = (const float*)d_in[2];
    const float* Wv   = (const float*)d_in[3];
    const float* Wo   = (const float*)d_in[4];
    const float* qsc  = (const float*)d_in[5];
    const float* ksc  = (const float*)d_in[6];
    const float* cosT = (const float*)d_in[7];
    const float* sinT = (const float*)d_in[8];

    f16* base = (f16*)d_ws;
    // persistent-through-attn buffers
    f16* xb   = base;                            // 0       .. 5,242,880   (dead after QKV gemm)
    f16* wcat = base + 5242880;                  //          .. 6,225,920  (dead after QKV gemm)
    f16* qkv  = base + 6225920;                  //          .. 18,808,832 (dead after transpose_v)
    f16* qh   = base + 18808832;                 //          .. 27,197,440
    f16* kh   = base + 27197440;                 //          .. 29,294,592
    f16* vt   = base + 29294592;                 //          .. 31,391,744
    f16* ctxb = base + 31391744;                 //          .. 39,780,352
    f16* wob  = base + 39780352;                 //          .. 40,435,712 (~81 MiB total)
    // attention partials OVERLAY the dead-by-then region [0 .. 17,039,360)
    f16*   pao = base;                           // 1024 x 64 x 256 f16 = 16,777,216
    float* pml = (float*)(base + 16777216);      // 1024 x 128 f32

    cvt_f32_f16<<<5120, 256, 0, stream>>>(x, xb, 1310720);
    cvt_f32_f16<<<640, 256, 0, stream>>>(Wq, wcat, 163840);
    cvt_f32_f16<<<160, 256, 0, stream>>>(Wk, wcat + 655360, 40960);
    cvt_f32_f16<<<160, 256, 0, stream>>>(Wv, wcat + 819200, 40960);
    cvt_f32_f16<<<640, 256, 0, stream>>>(Wo, wob, 163840);

    gemm_bt<false><<<dim3(64, 12), 256, 0, stream>>>(xb, wcat, qkv, 8192, 1536, 640);

    // q gets 1/16 scaling AND log2(e) folded in (scores computed in log2 domain)
    norm_rope<<<8192, 256, 0, stream>>>(qkv, 1536, 0,    qh, 1024, qsc, cosT, sinT, 2,
                                        0.0625f * 1.44269504f, 32768);
    norm_rope<<<2048, 256, 0, stream>>>(qkv, 1536, 1024, kh, 256,  ksc, cosT, sinT, 0,
                                        1.0f, 8192);

    transpose_v<<<dim3(64, 4, 2), 256, 0, stream>>>((const u16*)qkv, (u16*)vt);

    // split-K causal flash attention: 1024 equalized blocks (LPT order) + merge
    attn<<<1024, 256, 0, stream>>>(qh, kh, vt, pao, pml);
    merge_partials<<<512, 256, 0, stream>>>(pao, pml, ctxb);

    gemm_bt<true><<<dim3(64, 5), 256, 0, stream>>>(ctxb, wob, d_out, 8192, 640, 1024);
}